// Round 3
// baseline (1234.885 us; speedup 1.0000x reference)
//
#include <hip/hip_runtime.h>
#include <hip/hip_bf16.h>

#define NFEAT 128
#define ALPHA 0.2f
#define BSZ 128          // nodes per bucket
#define BSH 7            // log2(BSZ)
#define NBUK_MAX 1024    // scan padding; NBUK = ceil(N/BSZ) = 782 for N=100000
#define TILE 2048        // edges per partition tile

// ---------------- bucket CSR-lite build ----------------

__global__ __launch_bounds__(256) void k_zerob(int* __restrict__ bcnt, int nbuk) {
  int i = blockIdx.x * 256 + threadIdx.x;
  if (i < nbuk) bcnt[i] = 0;
}

__global__ __launch_bounds__(256) void k_bhist(const int* __restrict__ dst, int* __restrict__ bcnt,
                                               int E, int nbuk) {
  __shared__ int lh[NBUK_MAX];
  for (int i = threadIdx.x; i < nbuk; i += 256) lh[i] = 0;
  __syncthreads();
  int stride = gridDim.x * 256;
  for (int e = blockIdx.x * 256 + threadIdx.x; e < E; e += stride)
    atomicAdd(&lh[dst[e] >> BSH], 1);
  __syncthreads();
  for (int i = threadIdx.x; i < nbuk; i += 256)
    if (lh[i]) atomicAdd(&bcnt[i], lh[i]);
}

// 1 block: exclusive scan bcnt -> brow[0..nbuk], bfill = brow
__global__ __launch_bounds__(256) void k_bscan(const int* __restrict__ bcnt, int* __restrict__ brow,
                                               int* __restrict__ bfill, int nbuk, int E) {
  __shared__ int sc[NBUK_MAX];
  int t = threadIdx.x;
  #pragma unroll
  for (int k = 0; k < 4; ++k) { int i = t + k * 256; sc[i] = (i < nbuk) ? bcnt[i] : 0; }
  __syncthreads();
  for (int o = 1; o < NBUK_MAX; o <<= 1) {
    int a[4];
    #pragma unroll
    for (int k = 0; k < 4; ++k) { int i = t + k * 256; a[k] = (i >= o) ? sc[i - o] : 0; }
    __syncthreads();
    #pragma unroll
    for (int k = 0; k < 4; ++k) sc[t + k * 256] += a[k];
    __syncthreads();
  }
  #pragma unroll
  for (int k = 0; k < 4; ++k) {
    int i = t + k * 256;
    if (i < nbuk) { int ex = sc[i] - bcnt[i]; brow[i] = ex; bfill[i] = ex; }
  }
  if (t == 0) brow[nbuk] = E;
}

// partition edges into per-bucket contiguous regions; pack pair = (src<<BSH)|(dst&(BSZ-1))
__global__ __launch_bounds__(256) void k_bpart(const int* __restrict__ src, const int* __restrict__ dst,
    int* __restrict__ bfill, unsigned int* __restrict__ pairs, int E, int nbuk) {
  __shared__ unsigned long long spair[TILE];
  __shared__ int lh[NBUK_MAX];
  __shared__ int lo[NBUK_MAX];
  __shared__ int gbase[NBUK_MAX];
  __shared__ int lfill[NBUK_MAX];
  int t = threadIdx.x;
  int tb = blockIdx.x * TILE;
  int cnt = E - tb; if (cnt > TILE) cnt = TILE;
  int es[8], ed[8];
  #pragma unroll
  for (int k = 0; k < 8; ++k) {
    int li = k * 256 + t;
    bool v = li < cnt;
    es[k] = v ? src[tb + li] : 0;
    ed[k] = v ? dst[tb + li] : -1;
  }
  #pragma unroll
  for (int k = 0; k < 4; ++k) { lh[t + k * 256] = 0; lfill[t + k * 256] = 0; }
  __syncthreads();
  #pragma unroll
  for (int k = 0; k < 8; ++k) if (ed[k] >= 0) atomicAdd(&lh[ed[k] >> BSH], 1);
  __syncthreads();
  #pragma unroll
  for (int k = 0; k < 4; ++k) lo[t + k * 256] = lh[t + k * 256];
  __syncthreads();
  for (int o = 1; o < NBUK_MAX; o <<= 1) {
    int a[4];
    #pragma unroll
    for (int k = 0; k < 4; ++k) { int i = t + k * 256; a[k] = (i >= o) ? lo[i - o] : 0; }
    __syncthreads();
    #pragma unroll
    for (int k = 0; k < 4; ++k) lo[t + k * 256] += a[k];
    __syncthreads();
  }
  #pragma unroll
  for (int k = 0; k < 4; ++k) {
    int i = t + k * 256;
    lo[i] -= lh[i];                       // exclusive within tile
    if (i < nbuk && lh[i] > 0) gbase[i] = atomicAdd(&bfill[i], lh[i]);
  }
  __syncthreads();
  #pragma unroll
  for (int k = 0; k < 8; ++k) if (ed[k] >= 0) {
    int b = ed[k] >> BSH;
    int r = atomicAdd(&lfill[b], 1);
    spair[lo[b] + r] = ((unsigned long long)(unsigned int)es[k] << 32) | (unsigned int)ed[k];
  }
  __syncthreads();
  for (int i = t; i < cnt; i += 256) {
    unsigned long long p = spair[i];
    int d = (int)(unsigned int)p;
    int s = (int)(p >> 32);
    int b = d >> BSH;
    int gpos = gbase[b] + (i - lo[b]);
    pairs[gpos] = ((unsigned int)s << BSH) | (unsigned int)(d & (BSZ - 1));
  }
}

// per-bucket degree -> dis
__global__ __launch_bounds__(256) void k_bdis(const unsigned int* __restrict__ pairs,
    const int* __restrict__ brow, float* __restrict__ dis, int n) {
  __shared__ int lh[BSZ];
  int b = blockIdx.x, t = threadIdx.x;
  if (t < BSZ) lh[t] = 0;
  __syncthreads();
  int beg = brow[b], end = brow[b + 1];
  for (int j = beg + t; j < end; j += 256)
    atomicAdd(&lh[pairs[j] & (BSZ - 1)], 1);
  __syncthreads();
  int node = b * BSZ + t;
  if (t < BSZ && node < n) dis[node] = rsqrtf((float)(lh[t] + 1));
}

// ---------------- skinny GEMMs (W in LDS, thread = 1 row x 16 outs) ----------------

template<int K, int OW, bool HAS_BIAS, bool LEAKY, bool SCALE>
__global__ __launch_bounds__(256) void k_gemm(const float* __restrict__ A,
    const float* __restrict__ W, const float* __restrict__ bias,
    const float* __restrict__ dis, float* __restrict__ out, int n) {
  constexpr int TPR = OW / 16;
  constexpr int RPB = 256 / TPR;
  __shared__ float sW[K * OW];
  int t = threadIdx.x;
  {
    constexpr int NV = (K * OW) / (4 * 256);
    const float4* W4 = (const float4*)W;
    float4* s4 = (float4*)sW;
    #pragma unroll
    for (int i = 0; i < NV; ++i) s4[t + i * 256] = W4[t + i * 256];
  }
  __syncthreads();
  int row = blockIdx.x * RPB + t / TPR;
  if (row >= n) return;
  int og = (t % TPR) * 16;
  float acc[16];
  #pragma unroll
  for (int j = 0; j < 16; ++j) acc[j] = 0.f;
  const float4* a4 = (const float4*)(A + (size_t)row * K);
  #pragma unroll 4
  for (int k4 = 0; k4 < K / 4; ++k4) {
    float4 xv = a4[k4];
    const float* wr = &sW[(k4 * 4) * OW + og];
    #pragma unroll
    for (int j = 0; j < 16; ++j) acc[j] += xv.x * wr[j];
    #pragma unroll
    for (int j = 0; j < 16; ++j) acc[j] += xv.y * wr[OW + j];
    #pragma unroll
    for (int j = 0; j < 16; ++j) acc[j] += xv.z * wr[2 * OW + j];
    #pragma unroll
    for (int j = 0; j < 16; ++j) acc[j] += xv.w * wr[3 * OW + j];
  }
  float sc = SCALE ? dis[row] : 1.f;
  float* o = out + (size_t)row * OW + og;
  #pragma unroll
  for (int j = 0; j < 16; ++j) {
    float v = acc[j];
    if (HAS_BIAS) v += bias[og + j];
    if (SCALE) v *= sc;
    if (LEAKY) v = v > 0.f ? v : ALPHA * v;
    o[j] = v;
  }
}

// ---------------- bucket aggregation (fuses CSR fill away) ----------------

// conv1: 64 feats. lacc[BSZ][64] in LDS; h[d] = relu(dis[d]*(g[d]+acc)+b1)
__global__ __launch_bounds__(256) void k_agg1b(const float* __restrict__ g,
    const float* __restrict__ dis, const float* __restrict__ bias,
    const unsigned int* __restrict__ pairs, const int* __restrict__ brow,
    float* __restrict__ h, int n) {
  __shared__ float lacc[BSZ * 64];
  int t = threadIdx.x;
  float4* l4 = (float4*)lacc;
  #pragma unroll
  for (int k = 0; k < (BSZ * 64 / 4) / 256; ++k) l4[t + k * 256] = float4{0.f, 0.f, 0.f, 0.f};
  __syncthreads();
  int b = blockIdx.x;
  int beg = brow[b], cnt = brow[b + 1] - beg;
  int lane = t & 63, w = t >> 6;
  for (int base_i = w * 64; base_i < cnt; base_i += 256) {
    int m = cnt - base_i; if (m > 64) m = 64;
    unsigned int pk = pairs[beg + base_i + (lane < m ? lane : m - 1)];
    #pragma unroll 8
    for (int k = 0; k < m; ++k) {
      unsigned int u = __shfl(pk, k);
      float v = g[(size_t)(u >> BSH) * 64 + lane];
      atomicAdd(&lacc[(u & (BSZ - 1)) * 64 + lane], v);
    }
  }
  __syncthreads();
  int base_node = b * BSZ;
  float bl = bias[lane];
  for (int r = w; r < BSZ; r += 4) {
    int node = base_node + r;
    if (node < n) {
      float v = dis[node] * (g[(size_t)node * 64 + lane] + lacc[r * 64 + lane]) + bl;
      h[(size_t)node * 64 + lane] = v > 0.f ? v : 0.f;
    }
  }
}

// conv2 + final linear: 32 feats, two pairs per wave step (halves), fused W3 dot
__global__ __launch_bounds__(256) void k_agg2b(const float* __restrict__ g,
    const float* __restrict__ dis, const float* __restrict__ bias,
    const float* __restrict__ W3, const float* __restrict__ b3,
    const unsigned int* __restrict__ pairs, const int* __restrict__ brow,
    float* __restrict__ out, int n) {
  __shared__ float lacc[BSZ * 32];
  int t = threadIdx.x;
  float4* l4 = (float4*)lacc;
  #pragma unroll
  for (int k = 0; k < (BSZ * 32 / 4) / 256; ++k) l4[t + k * 256] = float4{0.f, 0.f, 0.f, 0.f};
  __syncthreads();
  int b = blockIdx.x;
  int beg = brow[b], cnt = brow[b + 1] - beg;
  int lane = t & 63, w = t >> 6;
  int f = lane & 31, half = lane >> 5;
  for (int base_i = w * 64; base_i < cnt; base_i += 256) {
    int m = cnt - base_i; if (m > 64) m = 64;
    unsigned int pk = pairs[beg + base_i + (lane < m ? lane : m - 1)];
    int mh = half ? (m > 32 ? m - 32 : 0) : (m < 32 ? m : 32);
    #pragma unroll 8
    for (int k = 0; k < mh; ++k) {
      unsigned int u = __shfl(pk, k + 32 * half);
      float v = g[(size_t)(u >> BSH) * 32 + f];
      atomicAdd(&lacc[(u & (BSZ - 1)) * 32 + f], v);
    }
  }
  __syncthreads();
  int base_node = b * BSZ;
  float w3 = W3[f], bf = bias[f];
  for (int r2 = w * 2; r2 < BSZ; r2 += 8) {
    int r = r2 + half;
    int node = base_node + r;
    float res = 0.f;
    bool ok = node < n;
    if (ok) {
      float v = dis[node] * (g[(size_t)node * 32 + f] + lacc[r * 32 + f]) + bf;
      v = v > 0.f ? v : 0.f;
      res = v * w3;
    }
    res += __shfl_xor(res, 16);
    res += __shfl_xor(res, 8);
    res += __shfl_xor(res, 4);
    res += __shfl_xor(res, 2);
    res += __shfl_xor(res, 1);
    if (f == 0 && ok) out[node] = res + b3[0];
  }
}

// ---------------- launch ----------------

extern "C" void kernel_launch(void* const* d_in, const int* in_sizes, int n_in,
                              void* d_out, int out_size, void* d_ws, size_t ws_size,
                              hipStream_t stream) {
  (void)n_in; (void)out_size; (void)ws_size;
  const float* x  = (const float*)d_in[0];
  const int*   ei = (const int*)d_in[2];
  const float* W0 = (const float*)d_in[3];
  const float* b0 = (const float*)d_in[4];
  const float* W1 = (const float*)d_in[5];
  const float* b1 = (const float*)d_in[6];
  const float* W2 = (const float*)d_in[7];
  const float* b2 = (const float*)d_in[8];
  const float* W3 = (const float*)d_in[9];
  const float* b3 = (const float*)d_in[10];
  float* out = (float*)d_out;
  int N = in_sizes[0] / NFEAT;
  int E = in_sizes[2] / 2;
  const int* src = ei;
  const int* dst = ei + E;
  int nbuk = (N + BSZ - 1) / BSZ;

  char* ws = (char*)d_ws;
  size_t off = 0;
  auto alloc = [&](size_t bytes) -> char* {
    char* p = ws + off;
    off += (bytes + 255) & ~(size_t)255;
    return p;
  };
  int*   bcnt  = (int*)alloc((size_t)nbuk * 4);
  int*   brow  = (int*)alloc((size_t)(nbuk + 1) * 4);
  int*   bfill = (int*)alloc((size_t)nbuk * 4);
  float* dis   = (float*)alloc((size_t)N * 4);
  unsigned int* pairs = (unsigned int*)alloc((size_t)E * 4);
  float* bufA  = (float*)alloc((size_t)N * 64 * 4);  // h0, then h1
  float* bufB  = (float*)alloc((size_t)N * 64 * 4);  // g1, then g2

  k_zerob<<<(nbuk + 255) / 256, 256, 0, stream>>>(bcnt, nbuk);
  k_bhist<<<128, 256, 0, stream>>>(dst, bcnt, E, nbuk);
  k_bscan<<<1, 256, 0, stream>>>(bcnt, brow, bfill, nbuk, E);
  k_bpart<<<(E + TILE - 1) / TILE, 256, 0, stream>>>(src, dst, bfill, pairs, E, nbuk);
  k_bdis<<<nbuk, 256, 0, stream>>>(pairs, brow, dis, N);

  // h0 = leaky_relu(x@W0 + b0) -> bufA
  k_gemm<NFEAT, 64, true, true, false><<<(N + 63) / 64, 256, 0, stream>>>(x, W0, b0, nullptr, bufA, N);
  // g1 = (h0@W1)*dis -> bufB
  k_gemm<64, 64, false, false, true><<<(N + 63) / 64, 256, 0, stream>>>(bufA, W1, nullptr, dis, bufB, N);
  // h1 = relu(dis*(g1[d] + sum g1[s]) + b1) -> bufA
  k_agg1b<<<nbuk, 256, 0, stream>>>(bufB, dis, b1, pairs, brow, bufA, N);
  // g2 = (h1@W2)*dis -> bufB
  k_gemm<64, 32, false, false, true><<<(N + 127) / 128, 256, 0, stream>>>(bufA, W2, nullptr, dis, bufB, N);
  // out = relu(dis*(g2[d] + sum g2[s]) + b2) @ W3 + b3
  k_agg2b<<<nbuk, 256, 0, stream>>>(bufB, dis, b2, W3, b3, pairs, brow, out, N);
}

// Round 4
// 311.959 us; speedup vs baseline: 3.9585x; 3.9585x over previous
//
#include <hip/hip_runtime.h>
#include <hip/hip_bf16.h>

#define NFEAT 128
#define ALPHA 0.2f
#define CBSH 10          // coarse bucket = 1024 nodes
#define CB   1024
#define NBMAX 128        // max coarse buckets (N=100000 -> 98)
#define TILE 4096        // edges per partition tile

// ---------------- CSR build (bucketed, coalesced) ----------------

// per-block LDS bucket hist, merged to global
__global__ __launch_bounds__(256) void k_bhist(const int* __restrict__ dst, int* __restrict__ bcnt,
                                               int E, int nbuk) {
  __shared__ int lh[NBMAX];
  int t = threadIdx.x;
  if (t < NBMAX) lh[t] = 0;
  __syncthreads();
  int stride = gridDim.x * 256;
  for (int e = blockIdx.x * 256 + t; e < E; e += stride)
    atomicAdd(&lh[dst[e] >> CBSH], 1);
  __syncthreads();
  if (t < nbuk && lh[t]) atomicAdd(&bcnt[t], lh[t]);
}

// 1 block: exclusive scan of nbuk (<128) bucket counts
__global__ __launch_bounds__(NBMAX) void k_bscan(const int* __restrict__ bcnt, int* __restrict__ brow,
                                                 int* __restrict__ bfill, int nbuk, int E) {
  __shared__ int sc[NBMAX];
  int t = threadIdx.x;
  int v = (t < nbuk) ? bcnt[t] : 0;
  sc[t] = v;
  __syncthreads();
  for (int o = 1; o < NBMAX; o <<= 1) {
    int u = (t >= o) ? sc[t - o] : 0;
    __syncthreads();
    sc[t] += u;
    __syncthreads();
  }
  int ex = sc[t] - v;
  if (t < nbuk) { brow[t] = ex; bfill[t] = ex; }
  if (t == 0) brow[nbuk] = E;
}

// partition edges into bucket-contiguous packed pairs: (src<<CBSH)|(dst&(CB-1))
__global__ __launch_bounds__(256) void k_bpart(const int* __restrict__ src, const int* __restrict__ dst,
    int* __restrict__ bfill, unsigned int* __restrict__ pairs, int E) {
  __shared__ unsigned long long sp[TILE];           // 32 KB
  __shared__ int lh[NBMAX], lo[NBMAX], gb[NBMAX], lf[NBMAX];
  int t = threadIdx.x;
  int tb = blockIdx.x * TILE;
  int cnt = E - tb; if (cnt > TILE) cnt = TILE;
  if (t < NBMAX) { lh[t] = 0; lf[t] = 0; }
  __syncthreads();
  int es[TILE / 256], ed[TILE / 256];
  #pragma unroll
  for (int k = 0; k < TILE / 256; ++k) {
    int li = k * 256 + t;
    bool v = li < cnt;
    es[k] = v ? src[tb + li] : 0;
    ed[k] = v ? dst[tb + li] : -1;
    if (v) atomicAdd(&lh[ed[k] >> CBSH], 1);
  }
  __syncthreads();
  if (t < NBMAX) lo[t] = lh[t];
  __syncthreads();
  for (int o = 1; o < NBMAX; o <<= 1) {
    int u = (t < NBMAX && t >= o) ? lo[t - o] : 0;
    __syncthreads();
    if (t < NBMAX) lo[t] += u;
    __syncthreads();
  }
  if (t < NBMAX) {
    lo[t] -= lh[t];                                  // exclusive within tile
    if (lh[t] > 0) gb[t] = atomicAdd(&bfill[t], lh[t]);
  }
  __syncthreads();
  #pragma unroll
  for (int k = 0; k < TILE / 256; ++k) if (ed[k] >= 0) {
    int bb = ed[k] >> CBSH;
    int r = atomicAdd(&lf[bb], 1);
    sp[lo[bb] + r] = ((unsigned long long)(unsigned int)es[k] << 32) | (unsigned int)ed[k];
  }
  __syncthreads();
  for (int i = t; i < cnt; i += 256) {
    unsigned long long p = sp[i];
    unsigned int d = (unsigned int)p;
    unsigned int s = (unsigned int)(p >> 32);
    int bb = d >> CBSH;
    pairs[gb[bb] + (i - lo[bb])] = (s << CBSH) | (d & (CB - 1));
  }
}

// per-bucket: degrees -> rowptr + dis, then scatter src into lst (block-local region)
__global__ __launch_bounds__(256) void k_bcsr(const unsigned int* __restrict__ pairs,
    const int* __restrict__ brow, int* __restrict__ rowptr, int* __restrict__ lst,
    float* __restrict__ dis, int n, int E) {
  __shared__ int deg[CB];
  __shared__ int pfx[CB];
  __shared__ int wsum[256];
  int b = blockIdx.x, t = threadIdx.x;
  int beg = brow[b], end = brow[b + 1];
  #pragma unroll
  for (int k = 0; k < CB / 256; ++k) deg[t + k * 256] = 0;
  __syncthreads();
  for (int i = beg + t; i < end; i += 256)
    atomicAdd(&deg[pairs[i] & (CB - 1)], 1);
  __syncthreads();
  // scan 1024 degrees: thread t owns 4t..4t+3
  int s0 = deg[4 * t], s1 = deg[4 * t + 1], s2 = deg[4 * t + 2], s3 = deg[4 * t + 3];
  int tsum = s0 + s1 + s2 + s3;
  wsum[t] = tsum;
  __syncthreads();
  for (int o = 1; o < 256; o <<= 1) {
    int u = (t >= o) ? wsum[t - o] : 0;
    __syncthreads();
    wsum[t] += u;
    __syncthreads();
  }
  int ex = wsum[t] - tsum;
  pfx[4 * t] = ex;
  pfx[4 * t + 1] = ex + s0;
  pfx[4 * t + 2] = ex + s0 + s1;
  pfx[4 * t + 3] = ex + s0 + s1 + s2;
  __syncthreads();
  int base_node = b << CBSH;
  #pragma unroll
  for (int k = 0; k < CB / 256; ++k) {
    int r = t + k * 256;
    int node = base_node + r;
    if (node < n) {
      rowptr[node] = beg + pfx[r];
      dis[node] = rsqrtf((float)(deg[r] + 1));
    }
  }
  if (b == 0 && t == 0) rowptr[n] = E;
  __syncthreads();
  // reuse deg[] as fill cursors (global positions)
  #pragma unroll
  for (int k = 0; k < CB / 256; ++k) {
    int r = t + k * 256;
    deg[r] = beg + pfx[r];
  }
  __syncthreads();
  for (int i = beg + t; i < end; i += 256) {
    unsigned int u = pairs[i];
    int p = atomicAdd(&deg[u & (CB - 1)], 1);
    lst[p] = (int)(u >> CBSH);
  }
}

// ---------------- skinny GEMMs (W in LDS, thread = 1 row x 16 outs) ----------------

template<int K, int OW, bool HAS_BIAS, bool LEAKY, bool SCALE>
__global__ __launch_bounds__(256) void k_gemm(const float* __restrict__ A,
    const float* __restrict__ W, const float* __restrict__ bias,
    const float* __restrict__ dis, float* __restrict__ out, int n) {
  constexpr int TPR = OW / 16;
  constexpr int RPB = 256 / TPR;
  __shared__ float sW[K * OW];
  int t = threadIdx.x;
  {
    constexpr int NV = (K * OW) / (4 * 256);
    const float4* W4 = (const float4*)W;
    float4* s4 = (float4*)sW;
    #pragma unroll
    for (int i = 0; i < NV; ++i) s4[t + i * 256] = W4[t + i * 256];
  }
  __syncthreads();
  int row = blockIdx.x * RPB + t / TPR;
  if (row >= n) return;
  int og = (t % TPR) * 16;
  float acc[16];
  #pragma unroll
  for (int j = 0; j < 16; ++j) acc[j] = 0.f;
  const float4* a4 = (const float4*)(A + (size_t)row * K);
  #pragma unroll 4
  for (int k4 = 0; k4 < K / 4; ++k4) {
    float4 xv = a4[k4];
    const float* wr = &sW[(k4 * 4) * OW + og];
    #pragma unroll
    for (int j = 0; j < 16; ++j) acc[j] += xv.x * wr[j];
    #pragma unroll
    for (int j = 0; j < 16; ++j) acc[j] += xv.y * wr[OW + j];
    #pragma unroll
    for (int j = 0; j < 16; ++j) acc[j] += xv.z * wr[2 * OW + j];
    #pragma unroll
    for (int j = 0; j < 16; ++j) acc[j] += xv.w * wr[3 * OW + j];
  }
  float sc = SCALE ? dis[row] : 1.f;
  float* o = out + (size_t)row * OW + og;
  #pragma unroll
  for (int j = 0; j < 16; ++j) {
    float v = acc[j];
    if (HAS_BIAS) v += bias[og + j];
    if (SCALE) v *= sc;
    if (LEAKY) v = v > 0.f ? v : ALPHA * v;
    o[j] = v;
  }
}

// ---------------- aggregation: wave per node ----------------

__global__ __launch_bounds__(256) void k_agg1(const float* __restrict__ g,
    const float* __restrict__ dis, const float* __restrict__ bias,
    const int* __restrict__ rowptr, const int* __restrict__ lst,
    float* __restrict__ h, int n) {
  int wid = (blockIdx.x * 256 + threadIdx.x) >> 6;
  if (wid >= n) return;
  int lane = threadIdx.x & 63;
  float acc = g[(size_t)wid * 64 + lane];
  int j = rowptr[wid], end = rowptr[wid + 1];
  for (; j + 4 <= end; j += 4) {
    int s0 = lst[j], s1 = lst[j + 1], s2 = lst[j + 2], s3 = lst[j + 3];
    acc += g[(size_t)s0 * 64 + lane];
    acc += g[(size_t)s1 * 64 + lane];
    acc += g[(size_t)s2 * 64 + lane];
    acc += g[(size_t)s3 * 64 + lane];
  }
  for (; j < end; ++j) acc += g[(size_t)lst[j] * 64 + lane];
  float v = dis[wid] * acc + bias[lane];
  h[(size_t)wid * 64 + lane] = v > 0.f ? v : 0.f;
}

__global__ __launch_bounds__(256) void k_agg2(const float* __restrict__ g,
    const float* __restrict__ dis, const float* __restrict__ bias,
    const float* __restrict__ W3, const float* __restrict__ b3,
    const int* __restrict__ rowptr, const int* __restrict__ lst,
    float* __restrict__ out, int n) {
  int wid = (blockIdx.x * 256 + threadIdx.x) >> 6;
  if (wid >= n) return;
  int lane = threadIdx.x & 63;
  int f = lane & 31, half = lane >> 5;
  float acc = (half == 0) ? g[(size_t)wid * 32 + f] : 0.f;
  int beg = rowptr[wid], end = rowptr[wid + 1];
  for (int j = beg + half; j < end; j += 2)
    acc += g[(size_t)lst[j] * 32 + f];
  acc += __shfl_down(acc, 32);
  float res = 0.f;
  if (half == 0) {
    float v = dis[wid] * acc + bias[f];
    v = v > 0.f ? v : 0.f;
    res = v * W3[f];
  }
  res += __shfl_xor(res, 16);
  res += __shfl_xor(res, 8);
  res += __shfl_xor(res, 4);
  res += __shfl_xor(res, 2);
  res += __shfl_xor(res, 1);
  if (lane == 0) out[wid] = res + b3[0];
}

// ---------------- launch ----------------

extern "C" void kernel_launch(void* const* d_in, const int* in_sizes, int n_in,
                              void* d_out, int out_size, void* d_ws, size_t ws_size,
                              hipStream_t stream) {
  (void)n_in; (void)out_size; (void)ws_size;
  const float* x  = (const float*)d_in[0];
  const int*   ei = (const int*)d_in[2];
  const float* W0 = (const float*)d_in[3];
  const float* b0 = (const float*)d_in[4];
  const float* W1 = (const float*)d_in[5];
  const float* b1 = (const float*)d_in[6];
  const float* W2 = (const float*)d_in[7];
  const float* b2 = (const float*)d_in[8];
  const float* W3 = (const float*)d_in[9];
  const float* b3 = (const float*)d_in[10];
  float* out = (float*)d_out;
  int N = in_sizes[0] / NFEAT;
  int E = in_sizes[2] / 2;
  const int* src = ei;
  const int* dst = ei + E;
  int nbuk = (N + CB - 1) / CB;

  char* ws = (char*)d_ws;
  size_t off = 0;
  auto alloc = [&](size_t bytes) -> char* {
    char* p = ws + off;
    off += (bytes + 255) & ~(size_t)255;
    return p;
  };
  int*   bcnt  = (int*)alloc((size_t)NBMAX * 4);
  int*   brow  = (int*)alloc((size_t)(NBMAX + 1) * 4);
  int*   bfill = (int*)alloc((size_t)NBMAX * 4);
  int*   rowp  = (int*)alloc((size_t)(N + 1) * 4);
  float* dis   = (float*)alloc((size_t)N * 4);
  unsigned int* pairs = (unsigned int*)alloc((size_t)E * 4);
  int*   lst   = (int*)alloc((size_t)E * 4);
  float* bufA  = (float*)alloc((size_t)N * 64 * 4);  // h0, then h1
  float* bufB  = (float*)alloc((size_t)N * 64 * 4);  // g1, then g2

  hipMemsetAsync(bcnt, 0, (size_t)NBMAX * 4, stream);
  k_bhist<<<256, 256, 0, stream>>>(dst, bcnt, E, nbuk);
  k_bscan<<<1, NBMAX, 0, stream>>>(bcnt, brow, bfill, nbuk, E);
  k_bpart<<<(E + TILE - 1) / TILE, 256, 0, stream>>>(src, dst, bfill, pairs, E);
  k_bcsr<<<nbuk, 256, 0, stream>>>(pairs, brow, rowp, lst, dis, N, E);

  // h0 = leaky_relu(x@W0 + b0) -> bufA
  k_gemm<NFEAT, 64, true, true, false><<<(N + 63) / 64, 256, 0, stream>>>(x, W0, b0, nullptr, bufA, N);
  // g1 = (h0@W1)*dis -> bufB
  k_gemm<64, 64, false, false, true><<<(N + 63) / 64, 256, 0, stream>>>(bufA, W1, nullptr, dis, bufB, N);
  // h1 = relu(dis*(g1[d] + sum g1[s]) + b1) -> bufA
  k_agg1<<<(N + 3) / 4, 256, 0, stream>>>(bufB, dis, b1, rowp, lst, bufA, N);
  // g2 = (h1@W2)*dis -> bufB
  k_gemm<64, 32, false, false, true><<<(N + 127) / 128, 256, 0, stream>>>(bufA, W2, nullptr, dis, bufB, N);
  // out = relu(dis*(g2[d] + sum g2[s]) + b2) @ W3 + b3
  k_agg2<<<(N + 3) / 4, 256, 0, stream>>>(bufB, dis, b2, W3, b3, rowp, lst, out, N);
}

// Round 5
// 246.515 us; speedup vs baseline: 5.0094x; 1.2655x over previous
//
#include <hip/hip_runtime.h>
#include <hip/hip_bf16.h>

#define NFEAT 128
#define ALPHA 0.2f
#define CBSH 10          // coarse bucket = 1024 nodes
#define CB   1024
#define NBMAX 128        // max coarse buckets (N=100000 -> 98)
#define TILE 4096        // edges per partition tile

// bf16 pair pack/unpack (RN-even)
__device__ inline unsigned int packbf2(float a, float b) {
  unsigned int ua = __float_as_uint(a), ub = __float_as_uint(b);
  ua = (ua + 0x7fffu + ((ua >> 16) & 1u)) >> 16;
  ub = (ub + 0x7fffu + ((ub >> 16) & 1u)) >> 16;
  return ua | (ub << 16);
}
__device__ inline void unpackbf2(unsigned int u, float& lo, float& hi) {
  lo = __uint_as_float(u << 16);
  hi = __uint_as_float(u & 0xffff0000u);
}

// ---------------- CSR build (bucketed, coalesced) ----------------

__global__ __launch_bounds__(256) void k_bhist(const int* __restrict__ dst, int* __restrict__ bcnt,
                                               int E, int nbuk) {
  __shared__ int lh[NBMAX];
  int t = threadIdx.x;
  if (t < NBMAX) lh[t] = 0;
  __syncthreads();
  int stride = gridDim.x * 256;
  for (int e = blockIdx.x * 256 + t; e < E; e += stride)
    atomicAdd(&lh[dst[e] >> CBSH], 1);
  __syncthreads();
  if (t < nbuk && lh[t]) atomicAdd(&bcnt[t], lh[t]);
}

__global__ __launch_bounds__(NBMAX) void k_bscan(const int* __restrict__ bcnt, int* __restrict__ brow,
                                                 int* __restrict__ bfill, int nbuk, int E) {
  __shared__ int sc[NBMAX];
  int t = threadIdx.x;
  int v = (t < nbuk) ? bcnt[t] : 0;
  sc[t] = v;
  __syncthreads();
  for (int o = 1; o < NBMAX; o <<= 1) {
    int u = (t >= o) ? sc[t - o] : 0;
    __syncthreads();
    sc[t] += u;
    __syncthreads();
  }
  int ex = sc[t] - v;
  if (t < nbuk) { brow[t] = ex; bfill[t] = ex; }
  if (t == 0) brow[nbuk] = E;
}

__global__ __launch_bounds__(256) void k_bpart(const int* __restrict__ src, const int* __restrict__ dst,
    int* __restrict__ bfill, unsigned int* __restrict__ pairs, int E) {
  __shared__ unsigned long long sp[TILE];           // 32 KB
  __shared__ int lh[NBMAX], lo[NBMAX], gb[NBMAX], lf[NBMAX];
  int t = threadIdx.x;
  int tb = blockIdx.x * TILE;
  int cnt = E - tb; if (cnt > TILE) cnt = TILE;
  if (t < NBMAX) { lh[t] = 0; lf[t] = 0; }
  __syncthreads();
  int es[TILE / 256], ed[TILE / 256];
  #pragma unroll
  for (int k = 0; k < TILE / 256; ++k) {
    int li = k * 256 + t;
    bool v = li < cnt;
    es[k] = v ? src[tb + li] : 0;
    ed[k] = v ? dst[tb + li] : -1;
    if (v) atomicAdd(&lh[ed[k] >> CBSH], 1);
  }
  __syncthreads();
  if (t < NBMAX) lo[t] = lh[t];
  __syncthreads();
  for (int o = 1; o < NBMAX; o <<= 1) {
    int u = (t < NBMAX && t >= o) ? lo[t - o] : 0;
    __syncthreads();
    if (t < NBMAX) lo[t] += u;
    __syncthreads();
  }
  if (t < NBMAX) {
    lo[t] -= lh[t];
    if (lh[t] > 0) gb[t] = atomicAdd(&bfill[t], lh[t]);
  }
  __syncthreads();
  #pragma unroll
  for (int k = 0; k < TILE / 256; ++k) if (ed[k] >= 0) {
    int bb = ed[k] >> CBSH;
    int r = atomicAdd(&lf[bb], 1);
    sp[lo[bb] + r] = ((unsigned long long)(unsigned int)es[k] << 32) | (unsigned int)ed[k];
  }
  __syncthreads();
  for (int i = t; i < cnt; i += 256) {
    unsigned long long p = sp[i];
    unsigned int d = (unsigned int)p;
    unsigned int s = (unsigned int)(p >> 32);
    int bb = d >> CBSH;
    pairs[gb[bb] + (i - lo[bb])] = (s << CBSH) | (d & (CB - 1));
  }
}

__global__ __launch_bounds__(256) void k_bcsr(const unsigned int* __restrict__ pairs,
    const int* __restrict__ brow, int* __restrict__ rowptr, int* __restrict__ lst,
    float* __restrict__ dis, int n, int E) {
  __shared__ int deg[CB];
  __shared__ int pfx[CB];
  __shared__ int wsum[256];
  int b = blockIdx.x, t = threadIdx.x;
  int beg = brow[b], end = brow[b + 1];
  #pragma unroll
  for (int k = 0; k < CB / 256; ++k) deg[t + k * 256] = 0;
  __syncthreads();
  for (int i = beg + t; i < end; i += 256)
    atomicAdd(&deg[pairs[i] & (CB - 1)], 1);
  __syncthreads();
  int s0 = deg[4 * t], s1 = deg[4 * t + 1], s2 = deg[4 * t + 2], s3 = deg[4 * t + 3];
  int tsum = s0 + s1 + s2 + s3;
  wsum[t] = tsum;
  __syncthreads();
  for (int o = 1; o < 256; o <<= 1) {
    int u = (t >= o) ? wsum[t - o] : 0;
    __syncthreads();
    wsum[t] += u;
    __syncthreads();
  }
  int ex = wsum[t] - tsum;
  pfx[4 * t] = ex;
  pfx[4 * t + 1] = ex + s0;
  pfx[4 * t + 2] = ex + s0 + s1;
  pfx[4 * t + 3] = ex + s0 + s1 + s2;
  __syncthreads();
  int base_node = b << CBSH;
  #pragma unroll
  for (int k = 0; k < CB / 256; ++k) {
    int r = t + k * 256;
    int node = base_node + r;
    if (node < n) {
      rowptr[node] = beg + pfx[r];
      dis[node] = rsqrtf((float)(deg[r] + 1));
    }
  }
  if (b == 0 && t == 0) rowptr[n] = E;
  __syncthreads();
  #pragma unroll
  for (int k = 0; k < CB / 256; ++k) {
    int r = t + k * 256;
    deg[r] = beg + pfx[r];
  }
  __syncthreads();
  for (int i = beg + t; i < end; i += 256) {
    unsigned int u = pairs[i];
    int p = atomicAdd(&deg[u & (CB - 1)], 1);
    lst[p] = (int)(u >> CBSH);
  }
}

// ---------------- skinny GEMMs (W in LDS, thread = 1 row x 16 outs) ----------------

template<int K, int OW, bool HAS_BIAS, bool LEAKY, bool SCALE, bool OBF>
__global__ __launch_bounds__(256) void k_gemm(const float* __restrict__ A,
    const float* __restrict__ W, const float* __restrict__ bias,
    const float* __restrict__ dis, void* __restrict__ outv, int n) {
  constexpr int TPR = OW / 16;
  constexpr int RPB = 256 / TPR;
  __shared__ float sW[K * OW];
  int t = threadIdx.x;
  {
    constexpr int NV = (K * OW) / (4 * 256);
    const float4* W4 = (const float4*)W;
    float4* s4 = (float4*)sW;
    #pragma unroll
    for (int i = 0; i < NV; ++i) s4[t + i * 256] = W4[t + i * 256];
  }
  __syncthreads();
  int row = blockIdx.x * RPB + t / TPR;
  if (row >= n) return;
  int og = (t % TPR) * 16;
  float acc[16];
  #pragma unroll
  for (int j = 0; j < 16; ++j) acc[j] = 0.f;
  const float4* a4 = (const float4*)(A + (size_t)row * K);
  #pragma unroll 4
  for (int k4 = 0; k4 < K / 4; ++k4) {
    float4 xv = a4[k4];
    const float* wr = &sW[(k4 * 4) * OW + og];
    #pragma unroll
    for (int j = 0; j < 16; ++j) acc[j] += xv.x * wr[j];
    #pragma unroll
    for (int j = 0; j < 16; ++j) acc[j] += xv.y * wr[OW + j];
    #pragma unroll
    for (int j = 0; j < 16; ++j) acc[j] += xv.z * wr[2 * OW + j];
    #pragma unroll
    for (int j = 0; j < 16; ++j) acc[j] += xv.w * wr[3 * OW + j];
  }
  float sc = SCALE ? dis[row] : 1.f;
  #pragma unroll
  for (int j = 0; j < 16; ++j) {
    float v = acc[j];
    if (HAS_BIAS) v += bias[og + j];
    if (SCALE) v *= sc;
    if (LEAKY) v = v > 0.f ? v : ALPHA * v;
    acc[j] = v;
  }
  if (OBF) {
    unsigned int* o = (unsigned int*)outv + (((size_t)row * OW + og) >> 1);
    #pragma unroll
    for (int j = 0; j < 8; ++j) o[j] = packbf2(acc[2 * j], acc[2 * j + 1]);
  } else {
    float* o = (float*)outv + (size_t)row * OW + og;
    #pragma unroll
    for (int j = 0; j < 16; ++j) o[j] = acc[j];
  }
}

// ---------------- aggregation: wave per node, bf16 gathers ----------------

// conv1: g = bf16[n][64] as uint[n][32]. 2 edges/wave-step (halves), 4x unroll -> 8 gathers in flight
__global__ __launch_bounds__(256) void k_agg1(const unsigned int* __restrict__ g,
    const float* __restrict__ dis, const float* __restrict__ bias,
    const int* __restrict__ rowptr, const int* __restrict__ lst,
    float* __restrict__ h, int n) {
  int wid = (blockIdx.x * 256 + threadIdx.x) >> 6;
  if (wid >= n) return;
  int lane = threadIdx.x & 63;
  int c = lane & 31, hh = lane >> 5;
  float a0 = 0.f, a1 = 0.f;
  if (hh == 0) unpackbf2(g[(size_t)wid * 32 + c], a0, a1);
  int beg = rowptr[wid], cnt = rowptr[wid + 1] - beg;
  for (int o = hh; o < cnt; o += 8) {
    int s0 = lst[beg + o];
    int s1 = (o + 2 < cnt) ? lst[beg + o + 2] : -1;
    int s2 = (o + 4 < cnt) ? lst[beg + o + 4] : -1;
    int s3 = (o + 6 < cnt) ? lst[beg + o + 6] : -1;
    unsigned int u0 = g[(size_t)s0 * 32 + c];
    unsigned int u1 = (s1 >= 0) ? g[(size_t)s1 * 32 + c] : 0u;
    unsigned int u2 = (s2 >= 0) ? g[(size_t)s2 * 32 + c] : 0u;
    unsigned int u3 = (s3 >= 0) ? g[(size_t)s3 * 32 + c] : 0u;
    float l0, h0, l1, h1, l2, h2, l3, h3;
    unpackbf2(u0, l0, h0); unpackbf2(u1, l1, h1);
    unpackbf2(u2, l2, h2); unpackbf2(u3, l3, h3);
    a0 += (l0 + l1) + (l2 + l3);
    a1 += (h0 + h1) + (h2 + h3);
  }
  a0 += __shfl_xor(a0, 32);
  a1 += __shfl_xor(a1, 32);
  if (hh == 0) {
    float d = dis[wid];
    float v0 = d * a0 + bias[2 * c];
    float v1 = d * a1 + bias[2 * c + 1];
    v0 = v0 > 0.f ? v0 : 0.f;
    v1 = v1 > 0.f ? v1 : 0.f;
    *(float2*)(h + (size_t)wid * 64 + 2 * c) = float2{v0, v1};
  }
}

// conv2 + final linear: g = bf16[n][32] as uint[n][16]. 4 edges/wave-step, 4x unroll -> 16 in flight
__global__ __launch_bounds__(256) void k_agg2(const unsigned int* __restrict__ g,
    const float* __restrict__ dis, const float* __restrict__ bias,
    const float* __restrict__ W3, const float* __restrict__ b3,
    const int* __restrict__ rowptr, const int* __restrict__ lst,
    float* __restrict__ out, int n) {
  int wid = (blockIdx.x * 256 + threadIdx.x) >> 6;
  if (wid >= n) return;
  int lane = threadIdx.x & 63;
  int c = lane & 15, q = lane >> 4;
  float a0 = 0.f, a1 = 0.f;
  if (q == 0) unpackbf2(g[(size_t)wid * 16 + c], a0, a1);
  int beg = rowptr[wid], cnt = rowptr[wid + 1] - beg;
  for (int o = q; o < cnt; o += 16) {
    int s0 = lst[beg + o];
    int s1 = (o + 4  < cnt) ? lst[beg + o + 4]  : -1;
    int s2 = (o + 8  < cnt) ? lst[beg + o + 8]  : -1;
    int s3 = (o + 12 < cnt) ? lst[beg + o + 12] : -1;
    unsigned int u0 = g[(size_t)s0 * 16 + c];
    unsigned int u1 = (s1 >= 0) ? g[(size_t)s1 * 16 + c] : 0u;
    unsigned int u2 = (s2 >= 0) ? g[(size_t)s2 * 16 + c] : 0u;
    unsigned int u3 = (s3 >= 0) ? g[(size_t)s3 * 16 + c] : 0u;
    float l0, h0, l1, h1, l2, h2, l3, h3;
    unpackbf2(u0, l0, h0); unpackbf2(u1, l1, h1);
    unpackbf2(u2, l2, h2); unpackbf2(u3, l3, h3);
    a0 += (l0 + l1) + (l2 + l3);
    a1 += (h0 + h1) + (h2 + h3);
  }
  a0 += __shfl_xor(a0, 32); a1 += __shfl_xor(a1, 32);
  a0 += __shfl_xor(a0, 16); a1 += __shfl_xor(a1, 16);
  float d = dis[wid];
  float v0 = d * a0 + bias[2 * c];
  float v1 = d * a1 + bias[2 * c + 1];
  v0 = v0 > 0.f ? v0 : 0.f;
  v1 = v1 > 0.f ? v1 : 0.f;
  float r = v0 * W3[2 * c] + v1 * W3[2 * c + 1];
  r += __shfl_xor(r, 8);
  r += __shfl_xor(r, 4);
  r += __shfl_xor(r, 2);
  r += __shfl_xor(r, 1);
  if (lane == 0) out[wid] = r + b3[0];
}

// ---------------- launch ----------------

extern "C" void kernel_launch(void* const* d_in, const int* in_sizes, int n_in,
                              void* d_out, int out_size, void* d_ws, size_t ws_size,
                              hipStream_t stream) {
  (void)n_in; (void)out_size; (void)ws_size;
  const float* x  = (const float*)d_in[0];
  const int*   ei = (const int*)d_in[2];
  const float* W0 = (const float*)d_in[3];
  const float* b0 = (const float*)d_in[4];
  const float* W1 = (const float*)d_in[5];
  const float* b1 = (const float*)d_in[6];
  const float* W2 = (const float*)d_in[7];
  const float* b2 = (const float*)d_in[8];
  const float* W3 = (const float*)d_in[9];
  const float* b3 = (const float*)d_in[10];
  float* out = (float*)d_out;
  int N = in_sizes[0] / NFEAT;
  int E = in_sizes[2] / 2;
  const int* src = ei;
  const int* dst = ei + E;
  int nbuk = (N + CB - 1) / CB;

  char* ws = (char*)d_ws;
  size_t off = 0;
  auto alloc = [&](size_t bytes) -> char* {
    char* p = ws + off;
    off += (bytes + 255) & ~(size_t)255;
    return p;
  };
  int*   bcnt  = (int*)alloc((size_t)NBMAX * 4);
  int*   brow  = (int*)alloc((size_t)(NBMAX + 1) * 4);
  int*   bfill = (int*)alloc((size_t)NBMAX * 4);
  int*   rowp  = (int*)alloc((size_t)(N + 1) * 4);
  float* dis   = (float*)alloc((size_t)N * 4);
  unsigned int* pairs = (unsigned int*)alloc((size_t)E * 4);
  int*   lst   = (int*)alloc((size_t)E * 4);
  float* bufA  = (float*)alloc((size_t)N * 64 * 4);          // h0, then h1 (fp32)
  unsigned int* bufG = (unsigned int*)alloc((size_t)N * 32 * 4);  // g1 then g2 (bf16 packed)

  hipMemsetAsync(bcnt, 0, (size_t)NBMAX * 4, stream);
  k_bhist<<<256, 256, 0, stream>>>(dst, bcnt, E, nbuk);
  k_bscan<<<1, NBMAX, 0, stream>>>(bcnt, brow, bfill, nbuk, E);
  k_bpart<<<(E + TILE - 1) / TILE, 256, 0, stream>>>(src, dst, bfill, pairs, E);
  k_bcsr<<<nbuk, 256, 0, stream>>>(pairs, brow, rowp, lst, dis, N, E);

  // h0 = leaky_relu(x@W0 + b0) -> bufA (fp32)
  k_gemm<NFEAT, 64, true, true, false, false><<<(N + 63) / 64, 256, 0, stream>>>(x, W0, b0, nullptr, bufA, N);
  // g1 = (h0@W1)*dis -> bufG (bf16)
  k_gemm<64, 64, false, false, true, true><<<(N + 63) / 64, 256, 0, stream>>>(bufA, W1, nullptr, dis, bufG, N);
  // h1 = relu(dis*(g1[d] + sum g1[s]) + b1) -> bufA (fp32)
  k_agg1<<<(N + 3) / 4, 256, 0, stream>>>(bufG, dis, b1, rowp, lst, bufA, N);
  // g2 = (h1@W2)*dis -> bufG (bf16)
  k_gemm<64, 32, false, false, true, true><<<(N + 127) / 128, 256, 0, stream>>>(bufA, W2, nullptr, dis, bufG, N);
  // out = relu(dis*(g2[d] + sum g2[s]) + b2) @ W3 + b3
  k_agg2<<<(N + 3) / 4, 256, 0, stream>>>(bufG, dis, b2, W3, b3, rowp, lst, out, N);
}

// Round 6
// 237.116 us; speedup vs baseline: 5.2079x; 1.0396x over previous
//
#include <hip/hip_runtime.h>
#include <hip/hip_bf16.h>

#define NFEAT 128
#define ALPHA 0.2f
#define CBSH 10          // coarse bucket = 1024 nodes
#define CB   1024
#define NBMAX 128        // max coarse buckets (N=100000 -> 98)
#define TILE 4096        // edges per partition tile

// bf16 pair pack/unpack (RN-even)
__device__ inline unsigned int packbf2(float a, float b) {
  unsigned int ua = __float_as_uint(a), ub = __float_as_uint(b);
  ua = (ua + 0x7fffu + ((ua >> 16) & 1u)) >> 16;
  ub = (ub + 0x7fffu + ((ub >> 16) & 1u)) >> 16;
  return ua | (ub << 16);
}
__device__ inline void unpackbf2(unsigned int u, float& lo, float& hi) {
  lo = __uint_as_float(u << 16);
  hi = __uint_as_float(u & 0xffff0000u);
}

// ---------------- CSR build (bucketed, coalesced) ----------------

__global__ __launch_bounds__(256) void k_bhist(const int* __restrict__ dst, int* __restrict__ bcnt,
                                               int E, int nbuk) {
  __shared__ int lh[NBMAX];
  int t = threadIdx.x;
  if (t < NBMAX) lh[t] = 0;
  __syncthreads();
  int stride = gridDim.x * 256;
  for (int e = blockIdx.x * 256 + t; e < E; e += stride)
    atomicAdd(&lh[dst[e] >> CBSH], 1);
  __syncthreads();
  if (t < nbuk && lh[t]) atomicAdd(&bcnt[t], lh[t]);
}

__global__ __launch_bounds__(NBMAX) void k_bscan(const int* __restrict__ bcnt, int* __restrict__ brow,
                                                 int* __restrict__ bfill, int nbuk, int E) {
  __shared__ int sc[NBMAX];
  int t = threadIdx.x;
  int v = (t < nbuk) ? bcnt[t] : 0;
  sc[t] = v;
  __syncthreads();
  for (int o = 1; o < NBMAX; o <<= 1) {
    int u = (t >= o) ? sc[t - o] : 0;
    __syncthreads();
    sc[t] += u;
    __syncthreads();
  }
  int ex = sc[t] - v;
  if (t < nbuk) { brow[t] = ex; bfill[t] = ex; }
  if (t == 0) brow[nbuk] = E;
}

__global__ __launch_bounds__(256) void k_bpart(const int* __restrict__ src, const int* __restrict__ dst,
    int* __restrict__ bfill, unsigned int* __restrict__ pairs, int E) {
  __shared__ unsigned long long sp[TILE];           // 32 KB
  __shared__ int lh[NBMAX], lo[NBMAX], gb[NBMAX], lf[NBMAX];
  int t = threadIdx.x;
  int tb = blockIdx.x * TILE;
  int cnt = E - tb; if (cnt > TILE) cnt = TILE;
  if (t < NBMAX) { lh[t] = 0; lf[t] = 0; }
  __syncthreads();
  int es[TILE / 256], ed[TILE / 256];
  #pragma unroll
  for (int k = 0; k < TILE / 256; ++k) {
    int li = k * 256 + t;
    bool v = li < cnt;
    es[k] = v ? src[tb + li] : 0;
    ed[k] = v ? dst[tb + li] : -1;
    if (v) atomicAdd(&lh[ed[k] >> CBSH], 1);
  }
  __syncthreads();
  if (t < NBMAX) lo[t] = lh[t];
  __syncthreads();
  for (int o = 1; o < NBMAX; o <<= 1) {
    int u = (t < NBMAX && t >= o) ? lo[t - o] : 0;
    __syncthreads();
    if (t < NBMAX) lo[t] += u;
    __syncthreads();
  }
  if (t < NBMAX) {
    lo[t] -= lh[t];
    if (lh[t] > 0) gb[t] = atomicAdd(&bfill[t], lh[t]);
  }
  __syncthreads();
  #pragma unroll
  for (int k = 0; k < TILE / 256; ++k) if (ed[k] >= 0) {
    int bb = ed[k] >> CBSH;
    int r = atomicAdd(&lf[bb], 1);
    sp[lo[bb] + r] = ((unsigned long long)(unsigned int)es[k] << 32) | (unsigned int)ed[k];
  }
  __syncthreads();
  for (int i = t; i < cnt; i += 256) {
    unsigned long long p = sp[i];
    unsigned int d = (unsigned int)p;
    unsigned int s = (unsigned int)(p >> 32);
    int bb = d >> CBSH;
    pairs[gb[bb] + (i - lo[bb])] = (s << CBSH) | (d & (CB - 1));
  }
}

__global__ __launch_bounds__(256) void k_bcsr(const unsigned int* __restrict__ pairs,
    const int* __restrict__ brow, int* __restrict__ rowptr, int* __restrict__ lst,
    float* __restrict__ dis, int n, int E) {
  __shared__ int deg[CB];
  __shared__ int pfx[CB];
  __shared__ int wsum[256];
  int b = blockIdx.x, t = threadIdx.x;
  int beg = brow[b], end = brow[b + 1];
  #pragma unroll
  for (int k = 0; k < CB / 256; ++k) deg[t + k * 256] = 0;
  __syncthreads();
  for (int i = beg + t; i < end; i += 256)
    atomicAdd(&deg[pairs[i] & (CB - 1)], 1);
  __syncthreads();
  int s0 = deg[4 * t], s1 = deg[4 * t + 1], s2 = deg[4 * t + 2], s3 = deg[4 * t + 3];
  int tsum = s0 + s1 + s2 + s3;
  wsum[t] = tsum;
  __syncthreads();
  for (int o = 1; o < 256; o <<= 1) {
    int u = (t >= o) ? wsum[t - o] : 0;
    __syncthreads();
    wsum[t] += u;
    __syncthreads();
  }
  int ex = wsum[t] - tsum;
  pfx[4 * t] = ex;
  pfx[4 * t + 1] = ex + s0;
  pfx[4 * t + 2] = ex + s0 + s1;
  pfx[4 * t + 3] = ex + s0 + s1 + s2;
  __syncthreads();
  int base_node = b << CBSH;
  #pragma unroll
  for (int k = 0; k < CB / 256; ++k) {
    int r = t + k * 256;
    int node = base_node + r;
    if (node < n) {
      rowptr[node] = beg + pfx[r];
      dis[node] = rsqrtf((float)(deg[r] + 1));
    }
  }
  if (b == 0 && t == 0) rowptr[n] = E;
  __syncthreads();
  #pragma unroll
  for (int k = 0; k < CB / 256; ++k) {
    int r = t + k * 256;
    deg[r] = beg + pfx[r];
  }
  __syncthreads();
  for (int i = beg + t; i < end; i += 256) {
    unsigned int u = pairs[i];
    int p = atomicAdd(&deg[u & (CB - 1)], 1);
    lst[p] = (int)(u >> CBSH);
  }
}

// ---------------- skinny GEMMs (W in LDS, thread = 1 row x 16 outs) ----------------

template<int K, int OW, bool HAS_BIAS, bool LEAKY, bool SCALE, bool OBF>
__global__ __launch_bounds__(256) void k_gemm(const float* __restrict__ A,
    const float* __restrict__ W, const float* __restrict__ bias,
    const float* __restrict__ dis, void* __restrict__ outv, int n) {
  constexpr int TPR = OW / 16;
  constexpr int RPB = 256 / TPR;
  __shared__ float sW[K * OW];
  int t = threadIdx.x;
  {
    constexpr int NV = (K * OW) / (4 * 256);
    const float4* W4 = (const float4*)W;
    float4* s4 = (float4*)sW;
    #pragma unroll
    for (int i = 0; i < NV; ++i) s4[t + i * 256] = W4[t + i * 256];
  }
  __syncthreads();
  int row = blockIdx.x * RPB + t / TPR;
  if (row >= n) return;
  int og = (t % TPR) * 16;
  float acc[16];
  #pragma unroll
  for (int j = 0; j < 16; ++j) acc[j] = 0.f;
  const float4* a4 = (const float4*)(A + (size_t)row * K);
  #pragma unroll 4
  for (int k4 = 0; k4 < K / 4; ++k4) {
    float4 xv = a4[k4];
    const float* wr = &sW[(k4 * 4) * OW + og];
    #pragma unroll
    for (int j = 0; j < 16; ++j) acc[j] += xv.x * wr[j];
    #pragma unroll
    for (int j = 0; j < 16; ++j) acc[j] += xv.y * wr[OW + j];
    #pragma unroll
    for (int j = 0; j < 16; ++j) acc[j] += xv.z * wr[2 * OW + j];
    #pragma unroll
    for (int j = 0; j < 16; ++j) acc[j] += xv.w * wr[3 * OW + j];
  }
  float sc = SCALE ? dis[row] : 1.f;
  #pragma unroll
  for (int j = 0; j < 16; ++j) {
    float v = acc[j];
    if (HAS_BIAS) v += bias[og + j];
    if (SCALE) v *= sc;
    if (LEAKY) v = v > 0.f ? v : ALPHA * v;
    acc[j] = v;
  }
  if (OBF) {
    unsigned int* o = (unsigned int*)outv + (((size_t)row * OW + og) >> 1);
    #pragma unroll
    for (int j = 0; j < 8; ++j) o[j] = packbf2(acc[2 * j], acc[2 * j + 1]);
  } else {
    float* o = (float*)outv + (size_t)row * OW + og;
    #pragma unroll
    for (int j = 0; j < 16; ++j) o[j] = acc[j];
  }
}

// ---------------- aggregation: wave per node, bf16 gathers, 8-deep MLP ----------------

// conv1: g = bf16[n][64] as uint[n][32]. 2 edges/wave-step (halves), 8x unroll -> 16 gathers in flight
__global__ __launch_bounds__(256) void k_agg1(const unsigned int* __restrict__ g,
    const float* __restrict__ dis, const float* __restrict__ bias,
    const int* __restrict__ rowptr, const int* __restrict__ lst,
    float* __restrict__ h, int n) {
  int wid = (blockIdx.x * 256 + threadIdx.x) >> 6;
  if (wid >= n) return;
  int lane = threadIdx.x & 63;
  int c = lane & 31, hh = lane >> 5;
  float a0 = 0.f, a1 = 0.f;
  if (hh == 0) unpackbf2(g[(size_t)wid * 32 + c], a0, a1);
  int beg = rowptr[wid], cnt = rowptr[wid + 1] - beg;
  for (int o = hh; o < cnt; o += 16) {
    int s[8];
    unsigned int u[8];
    #pragma unroll
    for (int k = 0; k < 8; ++k)
      s[k] = (o + 2 * k < cnt) ? lst[beg + o + 2 * k] : -1;
    #pragma unroll
    for (int k = 0; k < 8; ++k)
      u[k] = (s[k] >= 0) ? g[(size_t)s[k] * 32 + c] : 0u;
    #pragma unroll
    for (int k = 0; k < 8; ++k) {
      float lo, hi;
      unpackbf2(u[k], lo, hi);
      a0 += lo; a1 += hi;
    }
  }
  a0 += __shfl_xor(a0, 32);
  a1 += __shfl_xor(a1, 32);
  if (hh == 0) {
    float d = dis[wid];
    float v0 = d * a0 + bias[2 * c];
    float v1 = d * a1 + bias[2 * c + 1];
    v0 = v0 > 0.f ? v0 : 0.f;
    v1 = v1 > 0.f ? v1 : 0.f;
    *(float2*)(h + (size_t)wid * 64 + 2 * c) = float2{v0, v1};
  }
}

// conv2 + final linear: g = bf16[n][32] as uint[n][16]. 4 edges/wave-step, 8x unroll -> 32 in flight
__global__ __launch_bounds__(256) void k_agg2(const unsigned int* __restrict__ g,
    const float* __restrict__ dis, const float* __restrict__ bias,
    const float* __restrict__ W3, const float* __restrict__ b3,
    const int* __restrict__ rowptr, const int* __restrict__ lst,
    float* __restrict__ out, int n) {
  int wid = (blockIdx.x * 256 + threadIdx.x) >> 6;
  if (wid >= n) return;
  int lane = threadIdx.x & 63;
  int c = lane & 15, q = lane >> 4;
  float a0 = 0.f, a1 = 0.f;
  if (q == 0) unpackbf2(g[(size_t)wid * 16 + c], a0, a1);
  int beg = rowptr[wid], cnt = rowptr[wid + 1] - beg;
  for (int o = q; o < cnt; o += 32) {
    int s[8];
    unsigned int u[8];
    #pragma unroll
    for (int k = 0; k < 8; ++k)
      s[k] = (o + 4 * k < cnt) ? lst[beg + o + 4 * k] : -1;
    #pragma unroll
    for (int k = 0; k < 8; ++k)
      u[k] = (s[k] >= 0) ? g[(size_t)s[k] * 16 + c] : 0u;
    #pragma unroll
    for (int k = 0; k < 8; ++k) {
      float lo, hi;
      unpackbf2(u[k], lo, hi);
      a0 += lo; a1 += hi;
    }
  }
  a0 += __shfl_xor(a0, 32); a1 += __shfl_xor(a1, 32);
  a0 += __shfl_xor(a0, 16); a1 += __shfl_xor(a1, 16);
  float d = dis[wid];
  float v0 = d * a0 + bias[2 * c];
  float v1 = d * a1 + bias[2 * c + 1];
  v0 = v0 > 0.f ? v0 : 0.f;
  v1 = v1 > 0.f ? v1 : 0.f;
  float r = v0 * W3[2 * c] + v1 * W3[2 * c + 1];
  r += __shfl_xor(r, 8);
  r += __shfl_xor(r, 4);
  r += __shfl_xor(r, 2);
  r += __shfl_xor(r, 1);
  if (lane == 0) out[wid] = r + b3[0];
}

// ---------------- launch ----------------

extern "C" void kernel_launch(void* const* d_in, const int* in_sizes, int n_in,
                              void* d_out, int out_size, void* d_ws, size_t ws_size,
                              hipStream_t stream) {
  (void)n_in; (void)out_size; (void)ws_size;
  const float* x  = (const float*)d_in[0];
  const int*   ei = (const int*)d_in[2];
  const float* W0 = (const float*)d_in[3];
  const float* b0 = (const float*)d_in[4];
  const float* W1 = (const float*)d_in[5];
  const float* b1 = (const float*)d_in[6];
  const float* W2 = (const float*)d_in[7];
  const float* b2 = (const float*)d_in[8];
  const float* W3 = (const float*)d_in[9];
  const float* b3 = (const float*)d_in[10];
  float* out = (float*)d_out;
  int N = in_sizes[0] / NFEAT;
  int E = in_sizes[2] / 2;
  const int* src = ei;
  const int* dst = ei + E;
  int nbuk = (N + CB - 1) / CB;

  char* ws = (char*)d_ws;
  size_t off = 0;
  auto alloc = [&](size_t bytes) -> char* {
    char* p = ws + off;
    off += (bytes + 255) & ~(size_t)255;
    return p;
  };
  int*   bcnt  = (int*)alloc((size_t)NBMAX * 4);
  int*   brow  = (int*)alloc((size_t)(NBMAX + 1) * 4);
  int*   bfill = (int*)alloc((size_t)NBMAX * 4);
  int*   rowp  = (int*)alloc((size_t)(N + 1) * 4);
  float* dis   = (float*)alloc((size_t)N * 4);
  unsigned int* pairs = (unsigned int*)alloc((size_t)E * 4);
  int*   lst   = (int*)alloc((size_t)E * 4);
  float* bufA  = (float*)alloc((size_t)N * 64 * 4);          // h0, then h1 (fp32)
  unsigned int* bufG = (unsigned int*)alloc((size_t)N * 32 * 4);  // g1 then g2 (bf16 packed)

  hipMemsetAsync(bcnt, 0, (size_t)NBMAX * 4, stream);
  k_bhist<<<256, 256, 0, stream>>>(dst, bcnt, E, nbuk);
  k_bscan<<<1, NBMAX, 0, stream>>>(bcnt, brow, bfill, nbuk, E);
  k_bpart<<<(E + TILE - 1) / TILE, 256, 0, stream>>>(src, dst, bfill, pairs, E);
  k_bcsr<<<nbuk, 256, 0, stream>>>(pairs, brow, rowp, lst, dis, N, E);

  // h0 = leaky_relu(x@W0 + b0) -> bufA (fp32)
  k_gemm<NFEAT, 64, true, true, false, false><<<(N + 63) / 64, 256, 0, stream>>>(x, W0, b0, nullptr, bufA, N);
  // g1 = (h0@W1)*dis -> bufG (bf16)
  k_gemm<64, 64, false, false, true, true><<<(N + 63) / 64, 256, 0, stream>>>(bufA, W1, nullptr, dis, bufG, N);
  // h1 = relu(dis*(g1[d] + sum g1[s]) + b1) -> bufA (fp32)
  k_agg1<<<(N + 3) / 4, 256, 0, stream>>>(bufG, dis, b1, rowp, lst, bufA, N);
  // g2 = (h1@W2)*dis -> bufG (bf16)
  k_gemm<64, 32, false, false, true, true><<<(N + 127) / 128, 256, 0, stream>>>(bufA, W2, nullptr, dis, bufG, N);
  // out = relu(dis*(g2[d] + sum g2[s]) + b2) @ W3 + b3
  k_agg2<<<(N + 3) / 4, 256, 0, stream>>>(bufG, dis, b2, W3, b3, rowp, lst, out, N);
}

// Round 7
// 227.866 us; speedup vs baseline: 5.4194x; 1.0406x over previous
//
#include <hip/hip_runtime.h>
#include <hip/hip_bf16.h>

#define NFEAT 128
#define ALPHA 0.2f
#define CBSH 10          // coarse bucket = 1024 nodes
#define CB   1024
#define NBMAX 128        // max coarse buckets (N=100000 -> 98)
#define TILE 4096        // edges per partition tile

// bf16 pair pack/unpack (RN-even)
__device__ inline unsigned int packbf2(float a, float b) {
  unsigned int ua = __float_as_uint(a), ub = __float_as_uint(b);
  ua = (ua + 0x7fffu + ((ua >> 16) & 1u)) >> 16;
  ub = (ub + 0x7fffu + ((ub >> 16) & 1u)) >> 16;
  return ua | (ub << 16);
}
__device__ inline void unpackbf2(unsigned int u, float& lo, float& hi) {
  lo = __uint_as_float(u << 16);
  hi = __uint_as_float(u & 0xffff0000u);
}

// ---------------- CSR build (bucketed, coalesced) ----------------

__global__ __launch_bounds__(256) void k_bhist(const int* __restrict__ dst, int* __restrict__ bcnt,
                                               int E, int nbuk) {
  __shared__ int lh[NBMAX];
  int t = threadIdx.x;
  if (t < NBMAX) lh[t] = 0;
  __syncthreads();
  int stride = gridDim.x * 256;
  for (int e = blockIdx.x * 256 + t; e < E; e += stride)
    atomicAdd(&lh[dst[e] >> CBSH], 1);
  __syncthreads();
  if (t < nbuk && lh[t]) atomicAdd(&bcnt[t], lh[t]);
}

__global__ __launch_bounds__(NBMAX) void k_bscan(const int* __restrict__ bcnt, int* __restrict__ brow,
                                                 int* __restrict__ bfill, int nbuk, int E) {
  __shared__ int sc[NBMAX];
  int t = threadIdx.x;
  int v = (t < nbuk) ? bcnt[t] : 0;
  sc[t] = v;
  __syncthreads();
  for (int o = 1; o < NBMAX; o <<= 1) {
    int u = (t >= o) ? sc[t - o] : 0;
    __syncthreads();
    sc[t] += u;
    __syncthreads();
  }
  int ex = sc[t] - v;
  if (t < nbuk) { brow[t] = ex; bfill[t] = ex; }
  if (t == 0) brow[nbuk] = E;
}

__global__ __launch_bounds__(256) void k_bpart(const int* __restrict__ src, const int* __restrict__ dst,
    int* __restrict__ bfill, unsigned int* __restrict__ pairs, int E) {
  __shared__ unsigned long long sp[TILE];           // 32 KB
  __shared__ int lh[NBMAX], lo[NBMAX], gb[NBMAX], lf[NBMAX];
  int t = threadIdx.x;
  int tb = blockIdx.x * TILE;
  int cnt = E - tb; if (cnt > TILE) cnt = TILE;
  if (t < NBMAX) { lh[t] = 0; lf[t] = 0; }
  __syncthreads();
  int es[TILE / 256], ed[TILE / 256];
  #pragma unroll
  for (int k = 0; k < TILE / 256; ++k) {
    int li = k * 256 + t;
    bool v = li < cnt;
    es[k] = v ? src[tb + li] : 0;
    ed[k] = v ? dst[tb + li] : -1;
    if (v) atomicAdd(&lh[ed[k] >> CBSH], 1);
  }
  __syncthreads();
  if (t < NBMAX) lo[t] = lh[t];
  __syncthreads();
  for (int o = 1; o < NBMAX; o <<= 1) {
    int u = (t < NBMAX && t >= o) ? lo[t - o] : 0;
    __syncthreads();
    if (t < NBMAX) lo[t] += u;
    __syncthreads();
  }
  if (t < NBMAX) {
    lo[t] -= lh[t];
    if (lh[t] > 0) gb[t] = atomicAdd(&bfill[t], lh[t]);
  }
  __syncthreads();
  #pragma unroll
  for (int k = 0; k < TILE / 256; ++k) if (ed[k] >= 0) {
    int bb = ed[k] >> CBSH;
    int r = atomicAdd(&lf[bb], 1);
    sp[lo[bb] + r] = ((unsigned long long)(unsigned int)es[k] << 32) | (unsigned int)ed[k];
  }
  __syncthreads();
  for (int i = t; i < cnt; i += 256) {
    unsigned long long p = sp[i];
    unsigned int d = (unsigned int)p;
    unsigned int s = (unsigned int)(p >> 32);
    int bb = d >> CBSH;
    pairs[gb[bb] + (i - lo[bb])] = (s << CBSH) | (d & (CB - 1));
  }
}

__global__ __launch_bounds__(256) void k_bcsr(const unsigned int* __restrict__ pairs,
    const int* __restrict__ brow, int* __restrict__ rowptr, int* __restrict__ lst,
    float* __restrict__ dis, int n, int E) {
  __shared__ int deg[CB];
  __shared__ int pfx[CB];
  __shared__ int wsum[256];
  int b = blockIdx.x, t = threadIdx.x;
  int beg = brow[b], end = brow[b + 1];
  #pragma unroll
  for (int k = 0; k < CB / 256; ++k) deg[t + k * 256] = 0;
  __syncthreads();
  for (int i = beg + t; i < end; i += 256)
    atomicAdd(&deg[pairs[i] & (CB - 1)], 1);
  __syncthreads();
  int s0 = deg[4 * t], s1 = deg[4 * t + 1], s2 = deg[4 * t + 2], s3 = deg[4 * t + 3];
  int tsum = s0 + s1 + s2 + s3;
  wsum[t] = tsum;
  __syncthreads();
  for (int o = 1; o < 256; o <<= 1) {
    int u = (t >= o) ? wsum[t - o] : 0;
    __syncthreads();
    wsum[t] += u;
    __syncthreads();
  }
  int ex = wsum[t] - tsum;
  pfx[4 * t] = ex;
  pfx[4 * t + 1] = ex + s0;
  pfx[4 * t + 2] = ex + s0 + s1;
  pfx[4 * t + 3] = ex + s0 + s1 + s2;
  __syncthreads();
  int base_node = b << CBSH;
  #pragma unroll
  for (int k = 0; k < CB / 256; ++k) {
    int r = t + k * 256;
    int node = base_node + r;
    if (node < n) {
      rowptr[node] = beg + pfx[r];
      dis[node] = rsqrtf((float)(deg[r] + 1));
    }
  }
  if (b == 0 && t == 0) rowptr[n] = E;
  __syncthreads();
  #pragma unroll
  for (int k = 0; k < CB / 256; ++k) {
    int r = t + k * 256;
    deg[r] = beg + pfx[r];
  }
  __syncthreads();
  for (int i = beg + t; i < end; i += 256) {
    unsigned int u = pairs[i];
    int p = atomicAdd(&deg[u & (CB - 1)], 1);
    lst[p] = (int)(u >> CBSH);
  }
}

// ---------------- skinny GEMMs: wave-uniform W (scalar loads), lane = row ----------------
// wave w handles column group og = (w % WPC)*16 (wave-uniform -> s_load for W);
// lane = row within the block's row range; A read as coalesced float4;
// inner loop is pure v_fmac acc[j], a_k, s_w. No LDS at all.

template<int K, int OW, bool HAS_BIAS, bool LEAKY, bool SCALE, bool OBF>
__global__ __launch_bounds__(256) void k_gemm(const float* __restrict__ A,
    const float* __restrict__ W, const float* __restrict__ bias,
    const float* __restrict__ dis, void* __restrict__ outv, int n) {
  constexpr int WPC = OW / 16;               // waves per column span (4 or 2)
  constexpr int RPB = (4 / WPC) * 64;        // rows per block (64 or 128)
  int w = threadIdx.x >> 6, lane = threadIdx.x & 63;
  int og = __builtin_amdgcn_readfirstlane((w % WPC) * 16);
  int row = blockIdx.x * RPB + (w / WPC) * 64 + lane;
  bool ok = row < n;
  int rowc = ok ? row : 0;
  float acc[16];
  #pragma unroll
  for (int j = 0; j < 16; ++j) acc[j] = 0.f;
  const float4* a4 = (const float4*)(A + (size_t)rowc * K);
  const float* Wg = W + og;
  #pragma unroll 4
  for (int k4 = 0; k4 < K / 4; ++k4) {
    float4 xv = a4[k4];
    #pragma unroll
    for (int kk = 0; kk < 4; ++kk) {
      const float* wr = Wg + (k4 * 4 + kk) * OW;
      float xk = kk == 0 ? xv.x : kk == 1 ? xv.y : kk == 2 ? xv.z : xv.w;
      #pragma unroll
      for (int j = 0; j < 16; ++j) acc[j] += xk * wr[j];
    }
  }
  float sc = SCALE ? dis[rowc] : 1.f;
  #pragma unroll
  for (int j = 0; j < 16; ++j) {
    float v = acc[j];
    if (HAS_BIAS) v += bias[og + j];
    if (SCALE) v *= sc;
    if (LEAKY) v = v > 0.f ? v : ALPHA * v;
    acc[j] = v;
  }
  if (!ok) return;
  if (OBF) {
    uint4 p0, p1;
    p0.x = packbf2(acc[0], acc[1]);  p0.y = packbf2(acc[2], acc[3]);
    p0.z = packbf2(acc[4], acc[5]);  p0.w = packbf2(acc[6], acc[7]);
    p1.x = packbf2(acc[8], acc[9]);  p1.y = packbf2(acc[10], acc[11]);
    p1.z = packbf2(acc[12], acc[13]); p1.w = packbf2(acc[14], acc[15]);
    uint4* o = (uint4*)((unsigned int*)outv + (((size_t)row * OW + og) >> 1));
    o[0] = p0; o[1] = p1;
  } else {
    float4* o = (float4*)((float*)outv + (size_t)row * OW + og);
    o[0] = float4{acc[0], acc[1], acc[2], acc[3]};
    o[1] = float4{acc[4], acc[5], acc[6], acc[7]};
    o[2] = float4{acc[8], acc[9], acc[10], acc[11]};
    o[3] = float4{acc[12], acc[13], acc[14], acc[15]};
  }
}

// ---------------- aggregation: wave per node, bf16 uint2 gathers ----------------

// conv1: g row = 64 bf16 = 16 uint2. 16 lanes/edge -> 4 edges/step, 8x unroll (32 gathers in flight)
__global__ __launch_bounds__(256) void k_agg1(const unsigned int* __restrict__ g,
    const float* __restrict__ dis, const float* __restrict__ bias,
    const int* __restrict__ rowptr, const int* __restrict__ lst,
    float* __restrict__ h, int n) {
  int wid = (blockIdx.x * 256 + threadIdx.x) >> 6;
  if (wid >= n) return;
  int lane = threadIdx.x & 63;
  int c = lane & 15, q = lane >> 4;
  const uint2* g2 = (const uint2*)g;       // row stride = 16
  float a0 = 0.f, a1 = 0.f, a2 = 0.f, a3 = 0.f;
  if (q == 0) {
    uint2 u = g2[(size_t)wid * 16 + c];
    unpackbf2(u.x, a0, a1);
    unpackbf2(u.y, a2, a3);
  }
  int beg = rowptr[wid], cnt = rowptr[wid + 1] - beg;
  for (int o = q; o < cnt; o += 32) {
    int s[8];
    uint2 u[8];
    #pragma unroll
    for (int k = 0; k < 8; ++k)
      s[k] = (o + 4 * k < cnt) ? lst[beg + o + 4 * k] : -1;
    #pragma unroll
    for (int k = 0; k < 8; ++k)
      u[k] = (s[k] >= 0) ? g2[(size_t)s[k] * 16 + c] : uint2{0u, 0u};
    #pragma unroll
    for (int k = 0; k < 8; ++k) {
      float l0, h0, l1, h1;
      unpackbf2(u[k].x, l0, h0);
      unpackbf2(u[k].y, l1, h1);
      a0 += l0; a1 += h0; a2 += l1; a3 += h1;
    }
  }
  a0 += __shfl_xor(a0, 32); a1 += __shfl_xor(a1, 32);
  a2 += __shfl_xor(a2, 32); a3 += __shfl_xor(a3, 32);
  a0 += __shfl_xor(a0, 16); a1 += __shfl_xor(a1, 16);
  a2 += __shfl_xor(a2, 16); a3 += __shfl_xor(a3, 16);
  if (q == 0) {
    float d = dis[wid];
    float v0 = d * a0 + bias[4 * c];
    float v1 = d * a1 + bias[4 * c + 1];
    float v2 = d * a2 + bias[4 * c + 2];
    float v3 = d * a3 + bias[4 * c + 3];
    v0 = v0 > 0.f ? v0 : 0.f;
    v1 = v1 > 0.f ? v1 : 0.f;
    v2 = v2 > 0.f ? v2 : 0.f;
    v3 = v3 > 0.f ? v3 : 0.f;
    *(float4*)(h + (size_t)wid * 64 + 4 * c) = float4{v0, v1, v2, v3};
  }
}

// conv2 + final linear: g row = 32 bf16 = 8 uint2. 8 lanes/edge -> 8 edges/step, 4x unroll
__global__ __launch_bounds__(256) void k_agg2(const unsigned int* __restrict__ g,
    const float* __restrict__ dis, const float* __restrict__ bias,
    const float* __restrict__ W3, const float* __restrict__ b3,
    const int* __restrict__ rowptr, const int* __restrict__ lst,
    float* __restrict__ out, int n) {
  int wid = (blockIdx.x * 256 + threadIdx.x) >> 6;
  if (wid >= n) return;
  int lane = threadIdx.x & 63;
  int c = lane & 7, q = lane >> 3;
  const uint2* g2 = (const uint2*)g;       // row stride = 8
  float a0 = 0.f, a1 = 0.f, a2 = 0.f, a3 = 0.f;
  if (q == 0) {
    uint2 u = g2[(size_t)wid * 8 + c];
    unpackbf2(u.x, a0, a1);
    unpackbf2(u.y, a2, a3);
  }
  int beg = rowptr[wid], cnt = rowptr[wid + 1] - beg;
  for (int o = q; o < cnt; o += 32) {
    int s[4];
    uint2 u[4];
    #pragma unroll
    for (int k = 0; k < 4; ++k)
      s[k] = (o + 8 * k < cnt) ? lst[beg + o + 8 * k] : -1;
    #pragma unroll
    for (int k = 0; k < 4; ++k)
      u[k] = (s[k] >= 0) ? g2[(size_t)s[k] * 8 + c] : uint2{0u, 0u};
    #pragma unroll
    for (int k = 0; k < 4; ++k) {
      float l0, h0, l1, h1;
      unpackbf2(u[k].x, l0, h0);
      unpackbf2(u[k].y, l1, h1);
      a0 += l0; a1 += h0; a2 += l1; a3 += h1;
    }
  }
  a0 += __shfl_xor(a0, 32); a1 += __shfl_xor(a1, 32);
  a2 += __shfl_xor(a2, 32); a3 += __shfl_xor(a3, 32);
  a0 += __shfl_xor(a0, 16); a1 += __shfl_xor(a1, 16);
  a2 += __shfl_xor(a2, 16); a3 += __shfl_xor(a3, 16);
  a0 += __shfl_xor(a0, 8);  a1 += __shfl_xor(a1, 8);
  a2 += __shfl_xor(a2, 8);  a3 += __shfl_xor(a3, 8);
  float d = dis[wid];
  float v0 = d * a0 + bias[4 * c];
  float v1 = d * a1 + bias[4 * c + 1];
  float v2 = d * a2 + bias[4 * c + 2];
  float v3 = d * a3 + bias[4 * c + 3];
  v0 = v0 > 0.f ? v0 : 0.f;
  v1 = v1 > 0.f ? v1 : 0.f;
  v2 = v2 > 0.f ? v2 : 0.f;
  v3 = v3 > 0.f ? v3 : 0.f;
  float r = v0 * W3[4 * c] + v1 * W3[4 * c + 1] + v2 * W3[4 * c + 2] + v3 * W3[4 * c + 3];
  r += __shfl_xor(r, 4);
  r += __shfl_xor(r, 2);
  r += __shfl_xor(r, 1);
  if (lane == 0) out[wid] = r + b3[0];
}

// ---------------- launch ----------------

extern "C" void kernel_launch(void* const* d_in, const int* in_sizes, int n_in,
                              void* d_out, int out_size, void* d_ws, size_t ws_size,
                              hipStream_t stream) {
  (void)n_in; (void)out_size; (void)ws_size;
  const float* x  = (const float*)d_in[0];
  const int*   ei = (const int*)d_in[2];
  const float* W0 = (const float*)d_in[3];
  const float* b0 = (const float*)d_in[4];
  const float* W1 = (const float*)d_in[5];
  const float* b1 = (const float*)d_in[6];
  const float* W2 = (const float*)d_in[7];
  const float* b2 = (const float*)d_in[8];
  const float* W3 = (const float*)d_in[9];
  const float* b3 = (const float*)d_in[10];
  float* out = (float*)d_out;
  int N = in_sizes[0] / NFEAT;
  int E = in_sizes[2] / 2;
  const int* src = ei;
  const int* dst = ei + E;
  int nbuk = (N + CB - 1) / CB;

  char* ws = (char*)d_ws;
  size_t off = 0;
  auto alloc = [&](size_t bytes) -> char* {
    char* p = ws + off;
    off += (bytes + 255) & ~(size_t)255;
    return p;
  };
  int*   bcnt  = (int*)alloc((size_t)NBMAX * 4);
  int*   brow  = (int*)alloc((size_t)(NBMAX + 1) * 4);
  int*   bfill = (int*)alloc((size_t)NBMAX * 4);
  int*   rowp  = (int*)alloc((size_t)(N + 1) * 4);
  float* dis   = (float*)alloc((size_t)N * 4);
  unsigned int* pairs = (unsigned int*)alloc((size_t)E * 4);
  int*   lst   = (int*)alloc((size_t)E * 4);
  float* bufA  = (float*)alloc((size_t)N * 64 * 4);          // h0, then h1 (fp32)
  unsigned int* bufG = (unsigned int*)alloc((size_t)N * 32 * 4);  // g1 then g2 (bf16 packed)

  hipMemsetAsync(bcnt, 0, (size_t)NBMAX * 4, stream);
  k_bhist<<<256, 256, 0, stream>>>(dst, bcnt, E, nbuk);
  k_bscan<<<1, NBMAX, 0, stream>>>(bcnt, brow, bfill, nbuk, E);
  k_bpart<<<(E + TILE - 1) / TILE, 256, 0, stream>>>(src, dst, bfill, pairs, E);
  k_bcsr<<<nbuk, 256, 0, stream>>>(pairs, brow, rowp, lst, dis, N, E);

  // h0 = leaky_relu(x@W0 + b0) -> bufA (fp32)
  k_gemm<NFEAT, 64, true, true, false, false><<<(N + 63) / 64, 256, 0, stream>>>(x, W0, b0, nullptr, bufA, N);
  // g1 = (h0@W1)*dis -> bufG (bf16)
  k_gemm<64, 64, false, false, true, true><<<(N + 63) / 64, 256, 0, stream>>>(bufA, W1, nullptr, dis, bufG, N);
  // h1 = relu(dis*(g1[d] + sum g1[s]) + b1) -> bufA (fp32)
  k_agg1<<<(N + 3) / 4, 256, 0, stream>>>(bufG, dis, b1, rowp, lst, bufA, N);
  // g2 = (h1@W2)*dis -> bufG (bf16)
  k_gemm<64, 32, false, false, true, true><<<(N + 127) / 128, 256, 0, stream>>>(bufA, W2, nullptr, dis, bufG, N);
  // out = relu(dis*(g2[d] + sum g2[s]) + b2) @ W3 + b3
  k_agg2<<<(N + 3) / 4, 256, 0, stream>>>(bufG, dis, b2, W3, b3, rowp, lst, out, N);
}